// Round 10
// baseline (144.785 us; speedup 1.0000x reference)
//
#include <hip/hip_runtime.h>

// Navier-Stokes physics-informed loss (f32 in, scalar f32 out).
// x,y: (64,3,512,512). Interior: b in [1,62], i in [1,510], j in [1,510].
// r0 = |dudx + dvdy| ; r1 = |dudt + u*dudx + v*dudy + dpdx - MU*lap u| ;
// r2 = |dvdt + u*dvdx + v*dvdy + dpdy - MU*lap v|
// dudt = (u[b+1]-u[b-1])*32 ; d/dx,d/dy central *127.5 ; MU/DX^2 = 0.65025
//
// R4/R7/R9 plateau at wall ~142us across three structures; duration proven
// independent of HBM bytes (R9 replays: 73KB fetch, same time) and of
// requested bytes (1.17GB vs 0.66GB, same time). VALUBusy ~22% => 78% of
// cycles in waitcnt. Common to all: j-neighbor __shfl chains (12 DS ops/iter
// with lgkmcnt waits on the arithmetic critical path) + divergent edge-lane
// loads (or barriers in R9).
// R10: delete ALL cross-lane traffic. j+-1 via align-4 unaligned float4
// loads (c+-1): extra requested bytes overlap center cache lines, so L1/L2
// line traffic stays at R7 level; zero DS ops, zero divergence, p-center
// load dropped. Grid 255 x 5 b-chunks = 1275 <= 5 blocks/CU capacity
// (safe up to ~102 VGPR, single round, no tail).

constexpr int Wd   = 512;
constexpr int CSTR = 512 * 512;
constexpr int BSTR = 3 * 512 * 512;

__device__ __forceinline__ float4 ld4(const float* p) {          // 16B-aligned
    return *reinterpret_cast<const float4*>(p);
}
__device__ __forceinline__ float4 ld4u(const float* p) {         // align-4
    float4 v;
    __builtin_memcpy(&v, p, 16);
    return v;
}
__device__ __forceinline__ float4 scale4(float4 a, float s) {
    return make_float4(a.x * s, a.y * s, a.z * s, a.w * s);
}

// One tensor, one b-step, 4 columns. Carried centers (scaled): um,uc,vm,vc.
// All other operands loaded raw here. No shuffles, no branches.
__device__ __forceinline__ void step_tensor(
    const float* __restrict__ T, int c, float s, float sdx, float slap,
    float4& um, float4& uc, float4& vm, float4& vc,
    float r0[4], float r1[4], float r2[4])
{
    const float4 upn = ld4 (T + c + BSTR);               // u at b+1
    const float4 vpn = ld4 (T + c + BSTR + CSTR);        // v at b+1
    const float4 uxp = ld4 (T + c + Wd);                 // u row i+1
    const float4 uxm = ld4 (T + c - Wd);                 // u row i-1
    const float4 uyp = ld4u(T + c + 1);                  // u col j+1
    const float4 uym = ld4u(T + c - 1);                  // u col j-1
    const float4 vxp = ld4 (T + c + CSTR + Wd);
    const float4 vxm = ld4 (T + c + CSTR - Wd);
    const float4 vyp = ld4u(T + c + CSTR + 1);
    const float4 vym = ld4u(T + c + CSTR - 1);
    const float4 pxp = ld4 (T + c + 2 * CSTR + Wd);
    const float4 pxm = ld4 (T + c + 2 * CSTR - Wd);
    const float4 pyp = ld4u(T + c + 2 * CSTR + 1);
    const float4 pym = ld4u(T + c + 2 * CSTR - 1);

    const float ucA[4] = {uc.x, uc.y, uc.z, uc.w};
    const float vcA[4] = {vc.x, vc.y, vc.z, vc.w};
    const float umA[4] = {um.x, um.y, um.z, um.w};
    const float vmA[4] = {vm.x, vm.y, vm.z, vm.w};
    const float upA[4] = {upn.x, upn.y, upn.z, upn.w};
    const float vpA[4] = {vpn.x, vpn.y, vpn.z, vpn.w};
    const float uxpA[4] = {uxp.x, uxp.y, uxp.z, uxp.w};
    const float uxmA[4] = {uxm.x, uxm.y, uxm.z, uxm.w};
    const float uypA[4] = {uyp.x, uyp.y, uyp.z, uyp.w};
    const float uymA[4] = {uym.x, uym.y, uym.z, uym.w};
    const float vxpA[4] = {vxp.x, vxp.y, vxp.z, vxp.w};
    const float vxmA[4] = {vxm.x, vxm.y, vxm.z, vxm.w};
    const float vypA[4] = {vyp.x, vyp.y, vyp.z, vyp.w};
    const float vymA[4] = {vym.x, vym.y, vym.z, vym.w};
    const float pxpA[4] = {pxp.x, pxp.y, pxp.z, pxp.w};
    const float pxmA[4] = {pxm.x, pxm.y, pxm.z, pxm.w};
    const float pypA[4] = {pyp.x, pyp.y, pyp.z, pyp.w};
    const float pymA[4] = {pym.x, pym.y, pym.z, pym.w};

    #pragma unroll
    for (int k = 0; k < 4; ++k) {
        const float dudx = (uxpA[k] - uxmA[k]) * sdx;    // raw loads
        const float dudy = (uypA[k] - uymA[k]) * sdx;
        const float dvdx = (vxpA[k] - vxmA[k]) * sdx;
        const float dvdy = (vypA[k] - vymA[k]) * sdx;
        const float dpdx = (pxpA[k] - pxmA[k]) * sdx;
        const float dpdy = (pypA[k] - pymA[k]) * sdx;
        const float lapu = (uxpA[k] + uxmA[k] + uypA[k] + uymA[k]) * slap
                         - 2.601f * ucA[k];
        const float lapv = (vxpA[k] + vxmA[k] + vypA[k] + vymA[k]) * slap
                         - 2.601f * vcA[k];
        r0[k] = fabsf(dudx + dvdy);
        r1[k] = fabsf((upA[k] * s - umA[k]) * 32.0f
                      + ucA[k] * dudx + vcA[k] * dudy + dpdx - lapu);
        r2[k] = fabsf((vpA[k] * s - vmA[k]) * 32.0f
                      + ucA[k] * dvdx + vcA[k] * dvdy + dpdy - lapv);
    }

    um = uc; uc = scale4(upn, s);
    vm = vc; vc = scale4(vpn, s);
}

__global__ __launch_bounds__(256)
void ns_loss_kernel(const float* __restrict__ X, const float* __restrict__ Y,
                    const float* __restrict__ stdp, double* __restrict__ acc)
{
    const float s    = *stdp;
    const float sdx  = s * 127.5f;
    const float slap = s * 0.65025f;

    // m204 bijective XCD swizzle: nwg = 1275, q = 159, r = 3.
    // Ordering z-major, y-minor: each XCD owns contiguous i rows.
    const int orig = blockIdx.x;
    const int q    = 159, r = 3;
    const int xcd  = orig & 7;
    const int wg   = (xcd < r ? xcd * (q + 1) : r * (q + 1) + (xcd - r) * q)
                   + (orig >> 3);
    const int z = wg / 255;              // b-chunk 0..4
    const int y = wg % 255;              // i-pair 0..254

    const int tid = threadIdx.x;
    const int jt  = tid & 127;           // float4-column within row
    const int io  = tid >> 7;            // which of 2 rows
    const int i   = 1 + 2 * y + io;      // 1..510
    const int j0  = jt << 2;             // cols j0..j0+3, 0..511
    const int bs  = 1 + 13 * z;
    const int nsteps = min(13, 62 - 13 * z);   // 13,13,13,13,10

    int c = bs * BSTR + i * Wd + j0;

    float4 xum = scale4(ld4(X + c - BSTR), s);
    float4 xuc = scale4(ld4(X + c), s);
    float4 xvm = scale4(ld4(X + c - BSTR + CSTR), s);
    float4 xvc = scale4(ld4(X + c + CSTR), s);
    float4 yum = scale4(ld4(Y + c - BSTR), s);
    float4 yuc = scale4(ld4(Y + c), s);
    float4 yvm = scale4(ld4(Y + c - BSTR + CSTR), s);
    float4 yvc = scale4(ld4(Y + c + CSTR), s);

    const float w[4] = {(j0 != 0) ? 1.0f : 0.0f, 1.0f, 1.0f,
                        (j0 != 508) ? 1.0f : 0.0f};   // mask cols 0 and 511

    float s0 = 0.0f, s1 = 0.0f, s2 = 0.0f;

    for (int it = 0; it < nsteps; ++it) {
        float r0x[4], r1x[4], r2x[4], r0y[4], r1y[4], r2y[4];
        step_tensor(X, c, s, sdx, slap, xum, xuc, xvm, xvc, r0x, r1x, r2x);
        step_tensor(Y, c, s, sdx, slap, yum, yuc, yvm, yvc, r0y, r1y, r2y);
        #pragma unroll
        for (int k = 0; k < 4; ++k) {
            const float e0 = (r0y[k] - r0x[k]) * w[k];
            const float e1 = (r1y[k] - r1x[k]) * w[k];
            const float e2 = (r2y[k] - r2x[k]) * w[k];
            s0 += e0 * e0;
            s1 += e1 * e1;
            s2 += e2 * e2;
        }
        c += BSTR;
    }

    // block reduction: f32 wave shuffle -> LDS -> f64 atomic per block
    for (int o = 32; o > 0; o >>= 1) {
        s0 += __shfl_down(s0, o);
        s1 += __shfl_down(s1, o);
        s2 += __shfl_down(s2, o);
    }
    __shared__ float sm[3][4];
    const int wid = threadIdx.x >> 6, lane = threadIdx.x & 63;
    if (lane == 0) { sm[0][wid] = s0; sm[1][wid] = s1; sm[2][wid] = s2; }
    __syncthreads();
    if (threadIdx.x == 0) {
        atomicAdd(&acc[0], (double)sm[0][0] + (double)sm[0][1]
                         + (double)sm[0][2] + (double)sm[0][3]);
        atomicAdd(&acc[1], (double)sm[1][0] + (double)sm[1][1]
                         + (double)sm[1][2] + (double)sm[1][3]);
        atomicAdd(&acc[2], (double)sm[2][0] + (double)sm[2][1]
                         + (double)sm[2][2] + (double)sm[2][3]);
    }
}

__global__ void ns_finalize_kernel(const double* __restrict__ acc,
                                   float* __restrict__ out)
{
    if (threadIdx.x == 0) {
        const double N = 62.0 * 510.0 * 510.0;
        out[0] = (float)(1.0e-3 * (acc[0] + acc[1] + acc[2]) / N);
    }
}

extern "C" void kernel_launch(void* const* d_in, const int* in_sizes, int n_in,
                              void* d_out, int out_size, void* d_ws, size_t ws_size,
                              hipStream_t stream) {
    const float* X    = (const float*)d_in[0];
    const float* Y    = (const float*)d_in[1];
    const float* stdp = (const float*)d_in[2];
    float* out  = (float*)d_out;
    double* acc = (double*)d_ws;

    hipMemsetAsync(acc, 0, 3 * sizeof(double), stream);

    dim3 block(256);
    dim3 grid(255 * 5);   // 1275 blocks: single round even at 5 blocks/CU
    ns_loss_kernel<<<grid, block, 0, stream>>>(X, Y, stdp, acc);
    ns_finalize_kernel<<<1, 64, 0, stream>>>(acc, out);
}